// Round 2
// baseline (323.972 us; speedup 1.0000x reference)
//
#include <hip/hip_runtime.h>
#include <hip/hip_bf16.h>
#include <stdint.h>

// Problem: RMS-normalize rows of W [50257][768] fp32, then
// out = (||Wn^T Wn||_F^2 - sum_i ||wn_i||^4) * 0.5 / (V*(V-1)/2)
//
// Pipeline:
//  K0:  zero the two fp64 accumulators in ws
//  K12: fused — per 64-row strip: row sumsq -> r (LDS), diag_sq (fp64 atomic),
//       then scale+bf16+transpose strip into WnT[c][v] (strip re-read hits L2)
//  K3:  G tiles (upper triangle only) = WnT_I * WnT_J^T via bf16 MFMA,
//       split-K x24, fp32 partial tiles to ws
//  K4:  total_sq += weight * sum((sum_s partial)^2)  (fp64)
//  K5:  scalar combine -> d_out[0]

#define V_ROWS 50257
#define DIM 768
#define VPAD 50304            // 786 * 64, multiple of 64
#define NIT 786               // VPAD / 64  (K-iterations of 64)
#define SPLITS 24
#define CHUNK 33              // ceil(NIT / SPLITS)
#define NT 6                  // 768 / 128 tiles per dim
#define NTILES 21             // upper-triangle tile count
#define EPS 1.1920928955078125e-07f   // FLT_EPSILON = jnp.finfo(f32).eps

// ws layout (bytes)
#define WT_OFF  262144ull                      // bf16 WnT[768][VPAD] = 77,266,944 B
#define P_OFF   (262144ull + 77266944ull)      // float P[NTILES*SPLITS][128*128] = 33,030,144 B
// total ~110.6 MB

typedef __attribute__((ext_vector_type(8))) short bf16x8;
typedef __attribute__((ext_vector_type(4))) float f32x4;

__device__ __forceinline__ void gload_lds16(const void* g, void* l) {
    __builtin_amdgcn_global_load_lds(
        (const __attribute__((address_space(1))) void*)(g),
        (__attribute__((address_space(3))) void*)(l), 16, 0, 0);
}

__global__ void k0_zero(double* acc) {
    if (threadIdx.x < 2) acc[threadIdx.x] = 0.0;
}

// K12: fused norm + transpose. One block per 64-row strip (786 blocks).
// Phase 1: wave w computes sumsq of rows w*16..w*16+15 -> rv_s[64], diag_sq.
// Phase 2: for each of 12 column tiles, load 64x64 fp32 (L2-hit re-read),
//          scale by rv, cast bf16, transpose via LDS, store 16B/lane.
__global__ __launch_bounds__(256) void k12_norm_transpose(const float* __restrict__ W,
                                                          __hip_bfloat16* __restrict__ WT,
                                                          double* __restrict__ acc) {
    __shared__ float rv_s[64];
    __shared__ double part[4];
    __shared__ __hip_bfloat16 lds[64][80];   // [col][v], pad rows to 160B
    const int v0 = blockIdx.x * 64;
    const int w = threadIdx.x >> 6, lane = threadIdx.x & 63;

    double local = 0.0;
    #pragma unroll 1
    for (int i = 0; i < 16; ++i) {
        const int row = w * 16 + i;
        const int vv = v0 + row;
        float s = 0.f;
        if (vv < V_ROWS) {
            const float4* rowp = (const float4*)(W + (size_t)vv * DIM);
            #pragma unroll
            for (int j = 0; j < 3; ++j) {
                float4 x = rowp[lane + j * 64];
                s += x.x * x.x + x.y * x.y + x.z * x.z + x.w * x.w;
            }
        }
        #pragma unroll
        for (int off = 32; off; off >>= 1) s += __shfl_down(s, off);
        if (lane == 0) {
            float rv = (vv < V_ROWS) ? 1.0f / sqrtf(s * (1.0f / DIM) + EPS) : 0.0f;
            rv_s[row] = rv;
            float diag = s * rv * rv;              // ||wn||^2 (0 for pad rows)
            local += (double)diag * (double)diag;
        }
    }
    if (lane == 0) part[w] = local;
    __syncthreads();
    if (threadIdx.x == 0) atomicAdd(&acc[0], part[0] + part[1] + part[2] + part[3]);

    const int tid = threadIdx.x;
    const int rowg = tid >> 4, cq = tid & 15;    // load indices
    const int cl = tid >> 3, ch = tid & 7;       // store indices
    #pragma unroll 1
    for (int ct = 0; ct < 12; ++ct) {
        const int c0 = ct * 64;
        __syncthreads();                          // lds reuse guard
        #pragma unroll
        for (int rr = 0; rr < 4; ++rr) {
            const int row = rr * 16 + rowg;       // local v
            const int vv = v0 + row;
            float4 x = make_float4(0.f, 0.f, 0.f, 0.f);
            const float rv = rv_s[row];
            if (vv < V_ROWS)
                x = *(const float4*)(W + (size_t)vv * DIM + c0 + cq * 4);
            lds[cq * 4 + 0][row] = __float2bfloat16(x.x * rv);
            lds[cq * 4 + 1][row] = __float2bfloat16(x.y * rv);
            lds[cq * 4 + 2][row] = __float2bfloat16(x.z * rv);
            lds[cq * 4 + 3][row] = __float2bfloat16(x.w * rv);
        }
        __syncthreads();
        #pragma unroll
        for (int half = 0; half < 2; ++half) {
            const int c = cl + half * 32;
            float4 val = *(const float4*)(&lds[c][ch * 8]);
            *(float4*)(WT + (size_t)(c0 + c) * VPAD + v0 + ch * 8) = val;
        }
    }
}

// K3: bf16 MFMA Gram, 128x128 tile, KT=64, 4 waves, m97-style 2-barrier loop.
// LDS XOR-swizzle: 16B-block b of row r holds global k-block (b ^ (r&7)).
__global__ __launch_bounds__(256) void k3_gram(const unsigned short* __restrict__ WT,
                                               float* __restrict__ P) {
    __shared__ unsigned short lsA[128 * 64];
    __shared__ unsigned short lsB[128 * 64];
    const int bx = blockIdx.x;
    const int t = bx / SPLITS, s = bx % SPLITS;
    int tt = t, ti = 0, rem = NT;
    while (tt >= rem) { tt -= rem; --rem; ++ti; }
    const int tj = ti + tt;
    const int I = ti * 128, J = tj * 128;
    const int i0 = s * CHUNK;
    const int i1 = min(NIT, i0 + CHUNK);

    const int tid = threadIdx.x, lane = tid & 63, w = tid >> 6;
    const int wr = w >> 1, wc = w & 1;
    const int r16 = lane & 15, kq = lane >> 4;

    // staging: rep p covers LDS bytes [(p*4+w)*1024, +1024); lane writes 16B
    int srow[4], sblk[4], sbase[4];
    #pragma unroll
    for (int p = 0; p < 4; ++p) {
        const int base = (p * 4 + w) * 1024;
        const int o = base + lane * 16;
        srow[p] = o >> 7;                         // bf16 row (128B rows)
        sblk[p] = ((o >> 4) & 7) ^ (srow[p] & 7); // swizzled source k-block
        sbase[p] = base >> 1;                     // LDS element idx (wave-uniform)
    }

    // fragment read indices: row r, global k-block kb stored at kb^(r&7)
    int ia[4][2], ib[4][2];
    #pragma unroll
    for (int m = 0; m < 4; ++m) {
        const int ra = wr * 64 + m * 16 + r16;
        const int rb = wc * 64 + m * 16 + r16;
        #pragma unroll
        for (int kf = 0; kf < 2; ++kf) {
            ia[m][kf] = ra * 64 + (((kf * 4 + kq) ^ (ra & 7)) * 8);
            ib[m][kf] = rb * 64 + (((kf * 4 + kq) ^ (rb & 7)) * 8);
        }
    }

    f32x4 acc[4][4] = {};

    for (int it = i0; it < i1; ++it) {
        const int kv = it * 64;
        __syncthreads();
        #pragma unroll
        for (int p = 0; p < 4; ++p) {
            const unsigned short* ga = WT + (size_t)(I + srow[p]) * VPAD + kv + sblk[p] * 8;
            gload_lds16(ga, &lsA[sbase[p]]);
            const unsigned short* gb = WT + (size_t)(J + srow[p]) * VPAD + kv + sblk[p] * 8;
            gload_lds16(gb, &lsB[sbase[p]]);
        }
        __syncthreads();   // vmcnt(0) drain + barrier
        bf16x8 af[4][2], bfr[4][2];
        #pragma unroll
        for (int m = 0; m < 4; ++m) {
            #pragma unroll
            for (int kf = 0; kf < 2; ++kf) {
                af[m][kf]  = *(const bf16x8*)(&lsA[ia[m][kf]]);
                bfr[m][kf] = *(const bf16x8*)(&lsB[ib[m][kf]]);
            }
        }
        #pragma unroll
        for (int kf = 0; kf < 2; ++kf)
            #pragma unroll
            for (int m = 0; m < 4; ++m)
                #pragma unroll
                for (int n = 0; n < 4; ++n)
                    acc[m][n] = __builtin_amdgcn_mfma_f32_16x16x32_bf16(
                        af[m][kf], bfr[n][kf], acc[m][n], 0, 0, 0);
    }

    float* Pw = P + (size_t)bx * (128 * 128);
    #pragma unroll
    for (int m = 0; m < 4; ++m)
        #pragma unroll
        for (int n = 0; n < 4; ++n)
            #pragma unroll
            for (int j = 0; j < 4; ++j) {
                const int rr = wr * 64 + m * 16 + kq * 4 + j;  // C/D: row=(lane>>4)*4+j
                const int cc = wc * 64 + n * 16 + r16;         // col=lane&15
                Pw[rr * 128 + cc] = acc[m][n][j];
            }
}

// K4: total_sq += weight * sum_e (sum_s P[t,s,e])^2
__global__ __launch_bounds__(256) void k4_reduce(const float* __restrict__ P,
                                                 double* __restrict__ acc) {
    __shared__ double part[4];
    const int t = blockIdx.x, seg = blockIdx.y;
    int tt = t, ti = 0, rem = NT;
    while (tt >= rem) { tt -= rem; --rem; ++ti; }
    const int tj = ti + tt;
    const double wt = (ti == tj) ? 1.0 : 2.0;
    const int tid = threadIdx.x;
    double local = 0.0;
    for (int e = seg * 2048 + tid; e < (seg + 1) * 2048; e += 256) {
        float ssum = 0.f;
        #pragma unroll
        for (int s = 0; s < SPLITS; ++s)
            ssum += P[(size_t)(t * SPLITS + s) * 16384 + e];
        local += (double)ssum * (double)ssum;
    }
    #pragma unroll
    for (int off = 32; off; off >>= 1) local += __shfl_down(local, off);
    if ((tid & 63) == 0) part[tid >> 6] = local;
    __syncthreads();
    if (tid == 0) atomicAdd(&acc[1], (part[0] + part[1] + part[2] + part[3]) * wt);
}

__global__ void k5_final(const double* __restrict__ acc, float* __restrict__ out) {
    const double n_pairs = (double)V_ROWS * (double)(V_ROWS - 1) * 0.5;
    out[0] = (float)((acc[1] - acc[0]) * 0.5 / n_pairs);
}

extern "C" void kernel_launch(void* const* d_in, const int* in_sizes, int n_in,
                              void* d_out, int out_size, void* d_ws, size_t ws_size,
                              hipStream_t stream) {
    const float* W = (const float*)d_in[0];
    char* ws = (char*)d_ws;
    double* acc = (double*)ws;                                // [0]=diag_sq [1]=total_sq
    __hip_bfloat16* WT = (__hip_bfloat16*)(ws + WT_OFF);
    float* P = (float*)(ws + P_OFF);

    hipLaunchKernelGGL(k0_zero, dim3(1), dim3(64), 0, stream, acc);
    hipLaunchKernelGGL(k12_norm_transpose, dim3(VPAD / 64), dim3(256), 0, stream,
                       W, WT, acc);
    hipLaunchKernelGGL(k3_gram, dim3(NTILES * SPLITS), dim3(256), 0, stream,
                       (const unsigned short*)WT, P);
    hipLaunchKernelGGL(k4_reduce, dim3(NTILES, 8), dim3(256), 0, stream, P, acc);
    hipLaunchKernelGGL(k5_final, dim3(1), dim3(1), 0, stream, acc, (float*)d_out);
}

// Round 4
// 312.225 us; speedup vs baseline: 1.0376x; 1.0376x over previous
//
#include <hip/hip_runtime.h>
#include <hip/hip_bf16.h>
#include <stdint.h>

// Problem: RMS-normalize rows of W [50257][768] fp32, then
// out = (||Wn^T Wn||_F^2 - sum_i ||wn_i||^4) * 0.5 / (V*(V-1)/2)
//
// Pipeline:
//  K0:  zero the two fp64 accumulators in ws
//  K12: fused — per 64-row strip: parallel row sumsq (4 lanes/row) -> rv_s,
//       diag_sq (fp64 atomic), then scale+bf16+transpose strip into WnT[c][v]
//       via XOR-swizzled LDS (strip re-read hits L2; FETCH stays 1x W)
//  K3:  G tiles (upper triangle only) = WnT_I * WnT_J^T via bf16 MFMA,
//       split-K x24, fp32 partial tiles to ws
//  K4:  total_sq += weight * sum((sum_s partial)^2)  (fp64)
//  K5:  scalar combine -> d_out[0]

#define V_ROWS 50257
#define DIM 768
#define VPAD 50304            // 786 * 64, multiple of 64
#define NIT 786               // VPAD / 64  (K-iterations of 64)
#define SPLITS 24
#define CHUNK 33              // ceil(NIT / SPLITS)
#define NT 6                  // 768 / 128 tiles per dim
#define NTILES 21             // upper-triangle tile count
#define EPS 1.1920928955078125e-07f   // FLT_EPSILON = jnp.finfo(f32).eps

// ws layout (bytes)
#define WT_OFF  262144ull                      // bf16 WnT[768][VPAD] = 77,266,944 B
#define P_OFF   (262144ull + 77266944ull)      // float P[NTILES*SPLITS][128*128] = 33,030,144 B
// total ~110.6 MB

typedef __attribute__((ext_vector_type(8))) short bf16x8;
typedef __attribute__((ext_vector_type(4))) float f32x4;

__device__ __forceinline__ void gload_lds16(const void* g, void* l) {
    __builtin_amdgcn_global_load_lds(
        (const __attribute__((address_space(1))) void*)(g),
        (__attribute__((address_space(3))) void*)(l), 16, 0, 0);
}

__global__ void k0_zero(double* acc) {
    if (threadIdx.x < 2) acc[threadIdx.x] = 0.0;
}

// K12: fused norm + transpose, one block per 64-row strip (786 blocks).
// Phase 1: 4 lanes per row (64 rows in parallel), 64B-coalesced interleave.
// Phase 2: 12 column tiles; 64x64 fp32 L2-hit re-read, scale+bf16, transpose
//          via LDS with XOR block swizzle: element (c,v) stored at column
//          v ^ ((c>>2 & 7)<<3). Writes <=4-way banked, b128 reads clean.
__global__ __launch_bounds__(256) void k12_norm_transpose(const float* __restrict__ W,
                                                          __hip_bfloat16* __restrict__ WT,
                                                          double* __restrict__ acc) {
    __shared__ float rv_s[64];
    __shared__ double part[4];
    __shared__ __hip_bfloat16 lds2[64][64];   // [c][swizzled v], 8 KB
    const int v0 = blockIdx.x * 64;
    const int tid = threadIdx.x;
    const int w = tid >> 6, lane = tid & 63;

    // ---- Phase 1: row sumsq, 4 lanes/row ----
    const int prow = tid >> 2;            // 0..63
    const int q = tid & 3;                // quarter
    const int vv1 = v0 + prow;
    float s = 0.f;
    if (vv1 < V_ROWS) {
        const float4* rp = (const float4*)(W + (size_t)vv1 * DIM);
        #pragma unroll
        for (int j = 0; j < 48; ++j) {    // 4-lane group reads 64B contiguous
            float4 x = rp[q + j * 4];
            s += x.x * x.x + x.y * x.y + x.z * x.z + x.w * x.w;
        }
    }
    s += __shfl_xor(s, 1);
    s += __shfl_xor(s, 2);                // all 4 lanes: identical full sum
    const float rv = (vv1 < V_ROWS) ? 1.0f / sqrtf(s * (1.0f / DIM) + EPS) : 0.f;
    if (q == 0) rv_s[prow] = rv;
    double d = 0.0;
    if (q == 0 && vv1 < V_ROWS) {
        float dg = s * rv * rv;           // ||wn||^2
        d = (double)dg * (double)dg;
    }
    #pragma unroll
    for (int off = 32; off >= 4; off >>= 1) d += __shfl_down(d, off);
    if (lane == 0) part[w] = d;
    __syncthreads();
    if (tid == 0) atomicAdd(&acc[0], part[0] + part[1] + part[2] + part[3]);

    // ---- Phase 2: transpose 12 column tiles ----
    const int rowg = tid >> 4;            // 0..15 (load row group)
    const int cq = tid & 15;              // 0..15 (column quad)
    const int ksw = cq & 7;               // XOR key = (c>>2)&7 for c = cq*4+j
    const int cl = tid >> 3;              // 0..31 (store c row)
    const int ch = tid & 7;               // 0..7
    const int rk = ((ch ^ ((cl >> 2) & 7)) << 3);  // read start (c>>2&7 same for c, c+32)
    #pragma unroll 1
    for (int ct = 0; ct < 12; ++ct) {
        const int c0 = ct * 64;
        __syncthreads();                  // lds2 reuse guard
        #pragma unroll
        for (int rr = 0; rr < 4; ++rr) {
            const int row = rr * 16 + rowg;
            const int vv = v0 + row;
            float4 x = make_float4(0.f, 0.f, 0.f, 0.f);
            const float rvv = rv_s[row];
            if (vv < V_ROWS)
                x = *(const float4*)(W + (size_t)vv * DIM + c0 + cq * 4);
            const int p = row ^ (ksw << 3);
            lds2[cq * 4 + 0][p] = __float2bfloat16(x.x * rvv);
            lds2[cq * 4 + 1][p] = __float2bfloat16(x.y * rvv);
            lds2[cq * 4 + 2][p] = __float2bfloat16(x.z * rvv);
            lds2[cq * 4 + 3][p] = __float2bfloat16(x.w * rvv);
        }
        __syncthreads();
        #pragma unroll
        for (int half = 0; half < 2; ++half) {
            const int c = cl + half * 32;
            float4 val = *(const float4*)(&lds2[c][rk]);
            *(float4*)(WT + (size_t)(c0 + c) * VPAD + v0 + ch * 8) = val;
        }
    }
}

// K3: bf16 MFMA Gram, 128x128 tile, KT=64, 4 waves, m97-style 2-barrier loop.
// LDS XOR-swizzle: 16B-block b of row r holds global k-block (b ^ (r&7)).
__global__ __launch_bounds__(256) void k3_gram(const unsigned short* __restrict__ WT,
                                               float* __restrict__ P) {
    __shared__ unsigned short lsA[128 * 64];
    __shared__ unsigned short lsB[128 * 64];
    const int bx = blockIdx.x;
    const int t = bx / SPLITS, s = bx % SPLITS;
    int tt = t, ti = 0, rem = NT;
    while (tt >= rem) { tt -= rem; --rem; ++ti; }
    const int tj = ti + tt;
    const int I = ti * 128, J = tj * 128;
    const int i0 = s * CHUNK;
    const int i1 = min(NIT, i0 + CHUNK);

    const int tid = threadIdx.x, lane = tid & 63, w = tid >> 6;
    const int wr = w >> 1, wc = w & 1;
    const int r16 = lane & 15, kq = lane >> 4;

    // staging: rep p covers LDS bytes [(p*4+w)*1024, +1024); lane writes 16B
    int srow[4], sblk[4], sbase[4];
    #pragma unroll
    for (int p = 0; p < 4; ++p) {
        const int base = (p * 4 + w) * 1024;
        const int o = base + lane * 16;
        srow[p] = o >> 7;                         // bf16 row (128B rows)
        sblk[p] = ((o >> 4) & 7) ^ (srow[p] & 7); // swizzled source k-block
        sbase[p] = base >> 1;                     // LDS element idx (wave-uniform)
    }

    // fragment read indices: row r, global k-block kb stored at kb^(r&7)
    int ia[4][2], ib[4][2];
    #pragma unroll
    for (int m = 0; m < 4; ++m) {
        const int ra = wr * 64 + m * 16 + r16;
        const int rb = wc * 64 + m * 16 + r16;
        #pragma unroll
        for (int kf = 0; kf < 2; ++kf) {
            ia[m][kf] = ra * 64 + (((kf * 4 + kq) ^ (ra & 7)) * 8);
            ib[m][kf] = rb * 64 + (((kf * 4 + kq) ^ (rb & 7)) * 8);
        }
    }

    f32x4 acc[4][4] = {};

    for (int it = i0; it < i1; ++it) {
        const int kv = it * 64;
        __syncthreads();
        #pragma unroll
        for (int p = 0; p < 4; ++p) {
            const unsigned short* ga = WT + (size_t)(I + srow[p]) * VPAD + kv + sblk[p] * 8;
            gload_lds16(ga, &lsA[sbase[p]]);
            const unsigned short* gb = WT + (size_t)(J + srow[p]) * VPAD + kv + sblk[p] * 8;
            gload_lds16(gb, &lsB[sbase[p]]);
        }
        __syncthreads();   // vmcnt(0) drain + barrier
        bf16x8 af[4][2], bfr[4][2];
        #pragma unroll
        for (int m = 0; m < 4; ++m) {
            #pragma unroll
            for (int kf = 0; kf < 2; ++kf) {
                af[m][kf]  = *(const bf16x8*)(&lsA[ia[m][kf]]);
                bfr[m][kf] = *(const bf16x8*)(&lsB[ib[m][kf]]);
            }
        }
        #pragma unroll
        for (int kf = 0; kf < 2; ++kf)
            #pragma unroll
            for (int m = 0; m < 4; ++m)
                #pragma unroll
                for (int n = 0; n < 4; ++n)
                    acc[m][n] = __builtin_amdgcn_mfma_f32_16x16x32_bf16(
                        af[m][kf], bfr[n][kf], acc[m][n], 0, 0, 0);
    }

    float* Pw = P + (size_t)bx * (128 * 128);
    #pragma unroll
    for (int m = 0; m < 4; ++m)
        #pragma unroll
        for (int n = 0; n < 4; ++n)
            #pragma unroll
            for (int j = 0; j < 4; ++j) {
                const int rr = wr * 64 + m * 16 + kq * 4 + j;  // C/D: row=(lane>>4)*4+j
                const int cc = wc * 64 + n * 16 + r16;         // col=lane&15
                Pw[rr * 128 + cc] = acc[m][n][j];
            }
}

// K4: total_sq += weight * sum_e (sum_s P[t,s,e])^2
__global__ __launch_bounds__(256) void k4_reduce(const float* __restrict__ P,
                                                 double* __restrict__ acc) {
    __shared__ double part[4];
    const int t = blockIdx.x, seg = blockIdx.y;
    int tt = t, ti = 0, rem = NT;
    while (tt >= rem) { tt -= rem; --rem; ++ti; }
    const int tj = ti + tt;
    const double wt = (ti == tj) ? 1.0 : 2.0;
    const int tid = threadIdx.x;
    double local = 0.0;
    for (int e = seg * 2048 + tid; e < (seg + 1) * 2048; e += 256) {
        float ssum = 0.f;
        #pragma unroll
        for (int s = 0; s < SPLITS; ++s)
            ssum += P[(size_t)(t * SPLITS + s) * 16384 + e];
        local += (double)ssum * (double)ssum;
    }
    #pragma unroll
    for (int off = 32; off; off >>= 1) local += __shfl_down(local, off);
    if ((tid & 63) == 0) part[tid >> 6] = local;
    __syncthreads();
    if (tid == 0) atomicAdd(&acc[1], (part[0] + part[1] + part[2] + part[3]) * wt);
}

__global__ void k5_final(const double* __restrict__ acc, float* __restrict__ out) {
    const double n_pairs = (double)V_ROWS * (double)(V_ROWS - 1) * 0.5;
    out[0] = (float)((acc[1] - acc[0]) * 0.5 / n_pairs);
}

extern "C" void kernel_launch(void* const* d_in, const int* in_sizes, int n_in,
                              void* d_out, int out_size, void* d_ws, size_t ws_size,
                              hipStream_t stream) {
    const float* W = (const float*)d_in[0];
    char* ws = (char*)d_ws;
    double* acc = (double*)ws;                                // [0]=diag_sq [1]=total_sq
    __hip_bfloat16* WT = (__hip_bfloat16*)(ws + WT_OFF);
    float* P = (float*)(ws + P_OFF);

    hipLaunchKernelGGL(k0_zero, dim3(1), dim3(64), 0, stream, acc);
    hipLaunchKernelGGL(k12_norm_transpose, dim3(VPAD / 64), dim3(256), 0, stream,
                       W, WT, acc);
    hipLaunchKernelGGL(k3_gram, dim3(NTILES * SPLITS), dim3(256), 0, stream,
                       (const unsigned short*)WT, P);
    hipLaunchKernelGGL(k4_reduce, dim3(NTILES, 8), dim3(256), 0, stream, P, acc);
    hipLaunchKernelGGL(k5_final, dim3(1), dim3(1), 0, stream, acc, (float*)d_out);
}